// Round 7
// baseline (1074.013 us; speedup 1.0000x reference)
//
#include <hip/hip_runtime.h>
#include <math.h>

// TemporalGraphTower on MI355X (gfx950) — round 7.
// Weight-stationary k_nbr: 1024 blocks x 8 waves; each block owns one
// (layer, side) and 10 row-tiles; each wave holds its W1 strip (22 frags) and
// W2 hi/lo strip (16 frags) in registers for the whole block -> zero weight
// loads in steady state (was 3.2 TB of L2 re-reads = the round-5 stall).
// Numerics = rounds 1-5 proven: bf16 M1 single + fp32 rank-1 time fix,
// bf16 hi/lo 3-product M2, bf16 hi/lo 3-product GRU. k_event/prep = round 5.

typedef __bf16 bf16;
typedef __bf16 bf16x8 __attribute__((ext_vector_type(8)));
typedef float f32x4 __attribute__((ext_vector_type(4)));

#define MFMA16(a, b, c) __builtin_amdgcn_mfma_f32_16x16x32_bf16((a), (b), (c), 0, 0, 0)

__device__ __forceinline__ void split2(float v, bf16& hi, bf16& lo) {
  hi = (bf16)v;
  lo = (bf16)(v - (float)hi);
}

#define NB_EV 8192
#define ROWS_NB (NB_EV * 20)   // 163840
#define IN_DIM 352
#define HID 256
#define ND 128

// ---------------- prep: blocked weight layouts (round 5, proven) ----------
// W1blk  bf16 [2 l][11 k0][256 n][32 k]
// W2blk  bf16 [2 l][2 plane][8 kg][128 n][32 k]
// wihblk/whhblk bf16 [2 plane][4 kg][384 n][32 k]
// w320 f32 [2][256] — exact fp32 rank-1 fix for the big time column
__global__ void k_prep_weights(const float* __restrict__ W1, const float* __restrict__ W2,
                               const float* __restrict__ wih, const float* __restrict__ whh,
                               bf16* __restrict__ W1blk, bf16* __restrict__ W2blk,
                               bf16* __restrict__ wihblk, bf16* __restrict__ whhblk,
                               float* __restrict__ w320) {
  const int NW1 = 2 * 11 * 256 * 32;   // 180224
  const int NW2 = 2 * 2 * 8 * 128 * 32; // 131072
  const int NG = 2 * 4 * 384 * 32;     // 98304
  int total = NW1 + NW2 + NG + NG + 512;
  for (int i = blockIdx.x * blockDim.x + threadIdx.x; i < total; i += gridDim.x * blockDim.x) {
    int j = i;
    if (j < NW1) {
      int l = j / 90112, r = j - l * 90112;
      int k0 = r / 8192, r2 = r & 8191;
      int n = r2 >> 5, ko = r2 & 31, k = k0 * 32 + ko;
      W1blk[j] = (bf16)W1[(l * 352 + k) * 256 + n];
    } else if ((j -= NW1) < NW2) {
      int l = j >> 16, r = j & 65535;
      int plane = r >> 15, r2 = r & 32767;
      int kg = r2 >> 12, r3 = r2 & 4095;
      int n = r3 >> 5, ko = r3 & 31, k = kg * 32 + ko;
      bf16 hi, lo; split2(W2[(l * 256 + k) * 128 + n], hi, lo);
      W2blk[j] = plane ? lo : hi;
    } else if ((j -= NW2) < NG) {
      int plane = j / 49152, r = j - plane * 49152;
      int kg = r / 12288, r2 = r - kg * 12288;
      int n = r2 >> 5, ko = r2 & 31, k = kg * 32 + ko;
      bf16 hi, lo; split2(wih[n * 128 + k], hi, lo);
      wihblk[j] = plane ? lo : hi;
    } else if ((j -= NG) < NG) {
      int plane = j / 49152, r = j - plane * 49152;
      int kg = r / 12288, r2 = r - kg * 12288;
      int n = r2 >> 5, ko = r2 & 31, k = kg * 32 + ko;
      bf16 hi, lo; split2(whh[n * 128 + k], hi, lo);
      whhblk[j] = plane ? lo : hi;
    } else {
      j -= NG;
      int l = j >> 8, n = j & 255;
      w320[j] = W1[(l * 352 + 320) * 256 + n];
    }
  }
}

// time2vec table [B][32], initial embedding gathers, zero nb accumulators
__global__ void k_prep_misc(const float* __restrict__ ts, const float* __restrict__ w0,
                            const float* __restrict__ b0, const float* __restrict__ w,
                            const float* __restrict__ bb,
                            const int* __restrict__ srcn, const int* __restrict__ dstn,
                            const float* __restrict__ memory,
                            float* __restrict__ time_emb, float* __restrict__ embA0,
                            float* __restrict__ embB0, float* __restrict__ nb_out) {
  const int N1 = NB_EV * 32, N2 = NB_EV * ND, N3 = 4 * NB_EV * ND;
  int total = N1 + N2 + N3;
  float w0v = w0[0], b0v = b0[0];
  for (int i = blockIdx.x * blockDim.x + threadIdx.x; i < total; i += gridDim.x * blockDim.x) {
    int j = i;
    if (j < N1) {
      int b = j >> 5, c = j & 31;
      float t = ts[b];
      time_emb[j] = (c == 0) ? (w0v * t + b0v) : sinf(w[c - 1] * t + bb[c - 1]);
    } else if ((j -= N1) < N2) {
      int b = j >> 7, c = j & 127;
      embA0[j] = memory[(long)srcn[b] * ND + c];
      embB0[j] = memory[(long)dstn[b] * ND + c];
    } else {
      nb_out[j - N2] = 0.f;
    }
  }
}

__global__ void k_edge(const float* __restrict__ ea, const float* __restrict__ encW,
                       const float* __restrict__ encb, float* __restrict__ out) {
  __shared__ float row[64];
  int b = blockIdx.x, j = threadIdx.x;
  row[j] = ea[b * 64 + j];
  __syncthreads();
  float s = encb[j];
#pragma unroll
  for (int k = 0; k < 64; ++k) s += row[k] * encW[k * 64 + j];
  out[b * 64 + j] = s;
}

// ---------------- weight-stationary neighbor kernel ----------------
// grid 1024: bx&1=layer, (bx>>1)&1=side, bx>>2=chunk (10 tiles of 64 rows).
// 512 threads = 8 waves. Wave wid: M1 cols [wid*32,+32), M2 cols [wid*16,+16).
// T-mode MFMA (A=stationary weight frag, B=activation frag from LDS).
#define XSS 360        // xs stride (bf16 elems); 720B rows
#define HFS 264        // h full-plane stride (bf16 elems); 528B rows
#define N_XS 0         // 46080
#define N_HHI 46080    // 33792
#define N_HLO 79872    // 33792
#define N_CL 113664    // 256
#define N_TMP 113920   // 1024
#define N_TOT 114944
__global__ __launch_bounds__(512, 2) void k_nbr(
    const int* __restrict__ srcn, const int* __restrict__ dstn,
    const float* __restrict__ memory, const int* __restrict__ nbids,
    const float* __restrict__ nbt, const float* __restrict__ nbe,
    const float* __restrict__ w0p, const float* __restrict__ b0p,
    const float* __restrict__ wp, const float* __restrict__ bp,
    const bf16* __restrict__ W1blk, const bf16* __restrict__ W2blk,
    const float* __restrict__ w320, const float* __restrict__ b1,
    const float* __restrict__ b2, float* __restrict__ nb_out) {
  __shared__ __align__(16) char smem[N_TOT];
  bf16* xs = (bf16*)(smem + N_XS);
  bf16* hhi = (bf16*)(smem + N_HHI);
  bf16* hlo = (bf16*)(smem + N_HLO);
  float* cl = (float*)(smem + N_CL);
  int* nbid_l = (int*)(smem + N_TMP);
  int* n_l = nbid_l + 64;
  int* flat_l = n_l + 64;
  float* t_l = (float*)(flat_l + 64);

  const int tid = threadIdx.x;
  const int wid = tid >> 6, lane = tid & 63;
  const int colq = lane & 15, cq = lane >> 4;
  const int bx = blockIdx.x;
  const int layer = bx & 1, side = (bx >> 1) & 1, chunk = bx >> 2;
  const int* nodes = side ? dstn : srcn;

  // ---- stationary weights (loaded once, live for all 10 tiles)
  bf16x8 w1f[2][11];
  {
    const bf16* W1base = W1blk + layer * 90112 + (wid * 32 + colq) * 32 + cq * 8;
#pragma unroll
    for (int mc = 0; mc < 2; ++mc)
#pragma unroll
      for (int k0 = 0; k0 < 11; ++k0)
        w1f[mc][k0] = *(const bf16x8*)(W1base + mc * 512 + k0 * 8192);
  }
  bf16x8 w2h[8], w2l[8];
  {
    const bf16* W2base = W2blk + layer * 65536 + (wid * 16 + colq) * 32 + cq * 8;
#pragma unroll
    for (int kg = 0; kg < 8; ++kg) {
      w2h[kg] = *(const bf16x8*)(W2base + kg * 4096);
      w2l[kg] = *(const bf16x8*)(W2base + 32768 + kg * 4096);
    }
  }

  const float w0v = w0p[0], b0v = b0p[0];
  const float* w320l = w320 + layer * 256;
  const float* b1l = b1 + layer * 256;
  const float* b2l = b2 + layer * 128;
  const long zbase = (long)(layer * 2 + side) * NB_EV * ND;

  for (int t = 0; t < 10; ++t) {
    const int r0 = (chunk * 10 + t) * 64;

    if (tid < 64) {
      int rg = r0 + tid;
      int b = rg / 20, k = rg - b * 20;
      int n = nodes[b];
      int flat = n * 20 + k;
      nbid_l[tid] = nbids[flat];
      n_l[tid] = n;
      flat_l[tid] = flat;
      float tt = nbt[flat];
      t_l[tid] = tt;
      cl[tid] = w0v * tt + b0v;
    }
    __syncthreads();  // (1) temps ready; also fences last tile's M2 h-reads

    // build x tile: [nb_emb(128) | node_mem(128) | nb_e(64) | t2v(32, col0=0)]
    for (int task = tid; task < 64 * 88; task += 512) {
      int r = task / 88; int c = (task - r * 88) * 4;
      float4 v;
      if (c < 128) {
        v = *(const float4*)&memory[(long)nbid_l[r] * ND + c];
      } else if (c < 256) {
        v = *(const float4*)&memory[(long)n_l[r] * ND + (c - 128)];
      } else if (c < 320) {
        v = *(const float4*)&nbe[(long)flat_l[r] * 64 + (c - 256)];
      } else {
        float tt = t_l[r];
        float vv[4];
#pragma unroll
        for (int q = 0; q < 4; ++q) {
          int cc = c + q - 320;
          vv[q] = (cc == 0) ? 0.f : __sinf(wp[cc - 1] * tt + bp[cc - 1]);
        }
        v = make_float4(vv[0], vv[1], vv[2], vv[3]);
      }
      union { bf16 h[4]; uint2 u; } pk;
      pk.h[0] = (bf16)v.x; pk.h[1] = (bf16)v.y; pk.h[2] = (bf16)v.z; pk.h[3] = (bf16)v.w;
      *(uint2*)&xs[r * XSS + c] = pk.u;
    }
    __syncthreads();  // (2) xs ready

    // ---- M1-T: h = W1strip (A, stationary) x x-frags (B from LDS)
    const bf16* xsl = xs + colq * XSS + cq * 8;
    f32x4 acc[2][4];
#pragma unroll
    for (int mc = 0; mc < 2; ++mc)
#pragma unroll
      for (int nr = 0; nr < 4; ++nr) acc[mc][nr] = (f32x4){0.f, 0.f, 0.f, 0.f};
#pragma unroll
    for (int k0 = 0; k0 < 11; ++k0) {
      bf16x8 xb[4];
#pragma unroll
      for (int nr = 0; nr < 4; ++nr)
        xb[nr] = *(const bf16x8*)(xsl + nr * 16 * XSS + k0 * 32);
#pragma unroll
      for (int mc = 0; mc < 2; ++mc)
#pragma unroll
        for (int nr = 0; nr < 4; ++nr)
          acc[mc][nr] = MFMA16(w1f[mc][k0], xb[nr], acc[mc][nr]);
    }

    // rank-1 time fix + bias + relu; dump hi/lo (packed 8B, full-width plane)
#pragma unroll
    for (int mc = 0; mc < 2; ++mc) {
      int c0 = wid * 32 + mc * 16 + cq * 4;
      float4 wv = *(const float4*)&w320l[c0];
      float4 bv = *(const float4*)&b1l[c0];
#pragma unroll
      for (int nr = 0; nr < 4; ++nr) {
        float clr = cl[nr * 16 + colq];
        acc[mc][nr][0] = fmaxf(acc[mc][nr][0] + clr * wv.x + bv.x, 0.f);
        acc[mc][nr][1] = fmaxf(acc[mc][nr][1] + clr * wv.y + bv.y, 0.f);
        acc[mc][nr][2] = fmaxf(acc[mc][nr][2] + clr * wv.z + bv.z, 0.f);
        acc[mc][nr][3] = fmaxf(acc[mc][nr][3] + clr * wv.w + bv.w, 0.f);
        int r = nr * 16 + colq;
        union { bf16 h[4]; uint2 u; } ph, pl;
#pragma unroll
        for (int i = 0; i < 4; ++i) split2(acc[mc][nr][i], ph.h[i], pl.h[i]);
        *(uint2*)&hhi[r * HFS + c0] = ph.u;
        *(uint2*)&hlo[r * HFS + c0] = pl.u;
      }
    }
    __syncthreads();  // (3) h planes ready

    // ---- M2-T: m = W2strip (A, stationary hi/lo) x h-frags (B), 3 products
    const bf16* hb = hhi + colq * HFS + cq * 8;
    const bf16* lb = hlo + colq * HFS + cq * 8;
    f32x4 acc2[4];
#pragma unroll
    for (int nr = 0; nr < 4; ++nr) acc2[nr] = (f32x4){0.f, 0.f, 0.f, 0.f};
#pragma unroll
    for (int kg = 0; kg < 8; ++kg) {
      bf16x8 bh[4], blv[4];
#pragma unroll
      for (int nr = 0; nr < 4; ++nr) {
        bh[nr] = *(const bf16x8*)(hb + nr * 16 * HFS + kg * 32);
        blv[nr] = *(const bf16x8*)(lb + nr * 16 * HFS + kg * 32);
      }
#pragma unroll
      for (int nr = 0; nr < 4; ++nr) {
        acc2[nr] = MFMA16(w2h[kg], bh[nr], acc2[nr]);
        acc2[nr] = MFMA16(w2l[kg], bh[nr], acc2[nr]);
        acc2[nr] = MFMA16(w2h[kg], blv[nr], acc2[nr]);
      }
    }

    // ---- segmented mean over k (4 events per tile), registers + shfl only
    {
      int b0 = r0 / 20;
      int c0 = wid * 16 + cq * 4;
      float4 bv = *(const float4*)&b2l[c0];
#pragma unroll
      for (int e = 0; e < 4; ++e) {
        int b = b0 + e;
        int lo = b * 20 - r0, hi = lo + 20;
        int cnt = min(hi, 64) - max(lo, 0);
        if (cnt <= 0) continue;
        f32x4 v = (f32x4){0.f, 0.f, 0.f, 0.f};
#pragma unroll
        for (int nr = 0; nr < 4; ++nr) {
          int rl = nr * 16 + colq;
          if (rl >= lo && rl < hi) v += acc2[nr];
        }
#pragma unroll
        for (int s = 1; s < 16; s <<= 1) {
          v[0] += __shfl_xor(v[0], s);
          v[1] += __shfl_xor(v[1], s);
          v[2] += __shfl_xor(v[2], s);
          v[3] += __shfl_xor(v[3], s);
        }
        if (colq == e) {
          float fc = (float)cnt;
          atomicAdd(&nb_out[zbase + (long)b * ND + c0 + 0], (v[0] + fc * bv.x) * 0.05f);
          atomicAdd(&nb_out[zbase + (long)b * ND + c0 + 1], (v[1] + fc * bv.y) * 0.05f);
          atomicAdd(&nb_out[zbase + (long)b * ND + c0 + 2], (v[2] + fc * bv.z) * 0.05f);
          atomicAdd(&nb_out[zbase + (long)b * ND + c0 + 3], (v[3] + fc * bv.w) * 0.05f);
        }
      }
    }
  }
}

// ---------------- event chain: MLP + GRU (round 5, proven) ----------------
#define HSS 136
#define E_G 46080      // ghi @46080, glo @63488 (persist)
#define E_CL 80896
#define E_TOT 81152
__global__ __launch_bounds__(256, 1) void k_event(
    int layer, const float* __restrict__ embA_in, const float* __restrict__ embB_in,
    float* __restrict__ outA, int ostrideA, float* __restrict__ outB, int ostrideB,
    const float* __restrict__ time_emb, const float* __restrict__ edge_enc,
    const bf16* __restrict__ W1blk, const bf16* __restrict__ W2blk,
    const float* __restrict__ w320, const float* __restrict__ b1,
    const float* __restrict__ b2, const float* __restrict__ nb_out,
    const bf16* __restrict__ wihblk, const bf16* __restrict__ whhblk,
    const float* __restrict__ bih, const float* __restrict__ bhh) {
  __shared__ __align__(16) char smem[E_TOT];
  bf16* xs = (bf16*)(smem);
  bf16* hhi = (bf16*)(smem);                 // half-plane, overlays xs after M1
  bf16* hlo = (bf16*)(smem + 17408);
  bf16* mhi = (bf16*)(smem);                 // overlays h after M2
  bf16* mlo = (bf16*)(smem + 17408);
  bf16* ghi = (bf16*)(smem + E_G);
  bf16* glo = (bf16*)(smem + E_G + 17408);
  float* cl = (float*)(smem + E_CL);

  const int tid = threadIdx.x;
  const int r0 = blockIdx.x * 64;
  const int side = r0 >> 13;
  const int b0r = r0 & (NB_EV - 1);
  const float* ea = side ? embB_in : embA_in;   // own embedding (GRU h)
  const float* eb = side ? embA_in : embB_in;

  if (tid < 64) cl[tid] = time_emb[(b0r + tid) * 32];

  for (int task = tid; task < 64 * 88; task += 256) {
    int r = task / 88; int c = (task - r * 88) * 4;
    int b = b0r + r;
    float4 v;
    if (c < 128) {
      v = *(const float4*)&ea[(long)b * ND + c];
      bf16 h0, l0, h1, l1, h2, l2, h3, l3;
      split2(v.x, h0, l0); split2(v.y, h1, l1); split2(v.z, h2, l2); split2(v.w, h3, l3);
      ghi[r * HSS + c + 0] = h0; glo[r * HSS + c + 0] = l0;
      ghi[r * HSS + c + 1] = h1; glo[r * HSS + c + 1] = l1;
      ghi[r * HSS + c + 2] = h2; glo[r * HSS + c + 2] = l2;
      ghi[r * HSS + c + 3] = h3; glo[r * HSS + c + 3] = l3;
    } else if (c < 256) {
      v = *(const float4*)&eb[(long)b * ND + (c - 128)];
    } else if (c < 320) {
      v = *(const float4*)&edge_enc[(long)b * 64 + (c - 256)];
    } else {
      float vv[4];
#pragma unroll
      for (int q = 0; q < 4; ++q) {
        int cc = c + q - 320;
        vv[q] = (cc == 0) ? 0.f : time_emb[b * 32 + cc];
      }
      v = make_float4(vv[0], vv[1], vv[2], vv[3]);
    }
    union { bf16 h[4]; uint2 u; } pk;
    pk.h[0] = (bf16)v.x; pk.h[1] = (bf16)v.y; pk.h[2] = (bf16)v.z; pk.h[3] = (bf16)v.w;
    *(uint2*)&xs[r * XSS + c] = pk.u;
  }
  __syncthreads();

  const int wid = tid >> 6, lane = tid & 63;
  const int colq = lane & 15, cq = lane >> 4;
  const int rsub = cq * 4;

  // ---- M1 (A=x rows, B=W1)
  const bf16* W1l = W1blk + layer * 90112 + (wid * 64 + colq) * 32 + cq * 8;
  const bf16* xsl = xs + colq * XSS + cq * 8;
  f32x4 acc[4][4];
#pragma unroll
  for (int m = 0; m < 4; ++m)
#pragma unroll
    for (int n = 0; n < 4; ++n) acc[m][n] = (f32x4){0.f, 0.f, 0.f, 0.f};
#pragma unroll
  for (int k0 = 0; k0 < 11; ++k0) {
    bf16x8 a[4], b[4];
#pragma unroll
    for (int m = 0; m < 4; ++m) a[m] = *(const bf16x8*)(xsl + m * 16 * XSS + k0 * 32);
#pragma unroll
    for (int n = 0; n < 4; ++n) b[n] = *(const bf16x8*)(W1l + k0 * 8192 + n * 512);
#pragma unroll
    for (int m = 0; m < 4; ++m)
#pragma unroll
      for (int n = 0; n < 4; ++n) acc[m][n] = MFMA16(a[m], b[n], acc[m][n]);
  }
  __syncthreads();  // xs dead before h half overlay

  const float* w320l = w320 + layer * 256;
  const float* b1l = b1 + layer * 256;
#pragma unroll
  for (int n = 0; n < 4; ++n) {
    int cg = wid * 64 + n * 16 + colq;
    float wv = w320l[cg], bv = b1l[cg];
#pragma unroll
    for (int m = 0; m < 4; ++m)
#pragma unroll
      for (int i = 0; i < 4; ++i) {
        int r = m * 16 + rsub + i;
        acc[m][n][i] = fmaxf(acc[m][n][i] + cl[r] * wv + bv, 0.f);
      }
  }
  if (wid < 2) {
#pragma unroll
    for (int m = 0; m < 4; ++m)
#pragma unroll
      for (int n = 0; n < 4; ++n)
#pragma unroll
        for (int i = 0; i < 4; ++i) {
          int r = m * 16 + rsub + i;
          int cc = wid * 64 + n * 16 + colq;
          bf16 hi, lo; split2(acc[m][n][i], hi, lo);
          hhi[r * HSS + cc] = hi;
          hlo[r * HSS + cc] = lo;
        }
  }
  __syncthreads();

  // ---- M2 split-K (bf16 hi/lo, 3 products)
  const bf16* W2h = W2blk + layer * 65536 + (wid * 32 + colq) * 32 + cq * 8;
  const bf16* W2l = W2h + 32768;
  const bf16* hhil = hhi + colq * HSS + cq * 8;
  const bf16* hlol = hlo + colq * HSS + cq * 8;
  f32x4 acc2[4][2];
#pragma unroll
  for (int m = 0; m < 4; ++m)
#pragma unroll
    for (int n = 0; n < 2; ++n) acc2[m][n] = (f32x4){0.f, 0.f, 0.f, 0.f};
#pragma unroll
  for (int kg = 0; kg < 8; ++kg) {
    if (kg == 4) {
      __syncthreads();
      if (wid >= 2) {
#pragma unroll
        for (int m = 0; m < 4; ++m)
#pragma unroll
          for (int n = 0; n < 4; ++n)
#pragma unroll
            for (int i = 0; i < 4; ++i) {
              int r = m * 16 + rsub + i;
              int cc = (wid & 1) * 64 + n * 16 + colq;
              bf16 hi, lo; split2(acc[m][n][i], hi, lo);
              hhi[r * HSS + cc] = hi;
              hlo[r * HSS + cc] = lo;
            }
      }
      __syncthreads();
    }
    int lk = (kg & 3) * 32;
    bf16x8 ahi[4], alo[4], bhi[2], blo[2];
#pragma unroll
    for (int m = 0; m < 4; ++m) {
      ahi[m] = *(const bf16x8*)(hhil + m * 16 * HSS + lk);
      alo[m] = *(const bf16x8*)(hlol + m * 16 * HSS + lk);
    }
#pragma unroll
    for (int n = 0; n < 2; ++n) {
      bhi[n] = *(const bf16x8*)(W2h + kg * 4096 + n * 512);
      blo[n] = *(const bf16x8*)(W2l + kg * 4096 + n * 512);
    }
#pragma unroll
    for (int m = 0; m < 4; ++m)
#pragma unroll
      for (int n = 0; n < 2; ++n) {
        acc2[m][n] = MFMA16(ahi[m], bhi[n], acc2[m][n]);
        acc2[m][n] = MFMA16(ahi[m], blo[n], acc2[m][n]);
        acc2[m][n] = MFMA16(alo[m], bhi[n], acc2[m][n]);
      }
  }
  __syncthreads();  // h dead before m overlay

  const float* b2l = b2 + layer * 128;
  const float* nbl = nb_out + ((long)(layer * 2 + side)) * NB_EV * ND;
#pragma unroll
  for (int n = 0; n < 2; ++n) {
    int cg = wid * 32 + n * 16 + colq;
    float bv = b2l[cg];
#pragma unroll
    for (int m = 0; m < 4; ++m)
#pragma unroll
      for (int i = 0; i < 4; ++i) {
        int r = m * 16 + rsub + i;
        float mval = acc2[m][n][i] + bv + nbl[(long)(b0r + r) * ND + cg];
        bf16 hi, lo; split2(mval, hi, lo);
        mhi[r * HSS + cg] = hi;
        mlo[r * HSS + cg] = lo;
      }
  }
  __syncthreads();

  // ---- GRU: gate order (r,z,n)
  float* outP = side ? outB : outA;
  const int ostride = side ? ostrideB : ostrideA;
  const int rowA = wid * 16 + colq;
  const int rbase = wid * 16 + rsub;
  const bf16* mhil = mhi + rowA * HSS + cq * 8;
  const bf16* mlol = mlo + rowA * HSS + cq * 8;
  const bf16* ghil = ghi + rowA * HSS + cq * 8;
  const bf16* glol = glo + rowA * HSS + cq * 8;
  const bf16* wihl = wihblk + colq * 32 + cq * 8;
  const bf16* whhl = whhblk + colq * 32 + cq * 8;

  for (int jt = 0; jt < 8; ++jt) {
    f32x4 gx[3], gh[3];
#pragma unroll
    for (int g = 0; g < 3; ++g) {
      gx[g] = (f32x4){0.f, 0.f, 0.f, 0.f};
      gh[g] = (f32x4){0.f, 0.f, 0.f, 0.f};
    }
#pragma unroll
    for (int kc = 0; kc < 4; ++kc) {
      bf16x8 amh = *(const bf16x8*)(mhil + kc * 32);
      bf16x8 aml = *(const bf16x8*)(mlol + kc * 32);
      bf16x8 ahh = *(const bf16x8*)(ghil + kc * 32);
      bf16x8 ahl = *(const bf16x8*)(glol + kc * 32);
#pragma unroll
      for (int g = 0; g < 3; ++g) {
        int nb = (g * 128 + jt * 16) * 32;
        bf16x8 bh = *(const bf16x8*)(wihl + kc * 12288 + nb);
        bf16x8 bl = *(const bf16x8*)(wihl + 49152 + kc * 12288 + nb);
        gx[g] = MFMA16(amh, bh, gx[g]);
        gx[g] = MFMA16(aml, bh, gx[g]);
        gx[g] = MFMA16(amh, bl, gx[g]);
        bf16x8 ch = *(const bf16x8*)(whhl + kc * 12288 + nb);
        bf16x8 cl2 = *(const bf16x8*)(whhl + 49152 + kc * 12288 + nb);
        gh[g] = MFMA16(ahh, ch, gh[g]);
        gh[g] = MFMA16(ahl, ch, gh[g]);
        gh[g] = MFMA16(ahh, cl2, gh[g]);
      }
    }
    int j = jt * 16 + colq;
    float bihr = bih[j], bihz = bih[128 + j], bihn = bih[256 + j];
    float bhhr = bhh[j], bhhz = bhh[128 + j], bhhn = bhh[256 + j];
#pragma unroll
    for (int i = 0; i < 4; ++i) {
      int rr = rbase + i;
      float rx = gx[0][i] + bihr, zx = gx[1][i] + bihz, nx = gx[2][i] + bihn;
      float rh = gh[0][i] + bhhr, zh = gh[1][i] + bhhz, nh = gh[2][i] + bhhn;
      float r = 1.f / (1.f + expf(-(rx + rh)));
      float zz = 1.f / (1.f + expf(-(zx + zh)));
      float n = tanhf(nx + r * nh);
      float hval = (float)ghi[rr * HSS + j] + (float)glo[rr * HSS + j];
      outP[(long)(b0r + rr) * ostride + j] = (1.f - zz) * n + zz * hval;
    }
  }
}

// ---------------- launch ----------------
extern "C" void kernel_launch(void* const* d_in, const int* in_sizes, int n_in,
                              void* d_out, int out_size, void* d_ws, size_t ws_size,
                              hipStream_t stream) {
  const int* srcn = (const int*)d_in[0];
  const int* dstn = (const int*)d_in[1];
  const float* edge_attrs = (const float*)d_in[2];
  const float* timestamps = (const float*)d_in[3];
  const float* memory = (const float*)d_in[4];
  const int* neighbor_ids = (const int*)d_in[5];
  const float* neighbor_times = (const float*)d_in[6];
  const float* neighbor_edge_attrs = (const float*)d_in[7];
  const float* t2v_w0 = (const float*)d_in[8];
  const float* t2v_b0 = (const float*)d_in[9];
  const float* t2v_w = (const float*)d_in[10];
  const float* t2v_b = (const float*)d_in[11];
  const float* enc_W = (const float*)d_in[12];
  const float* enc_b = (const float*)d_in[13];
  const float* mlp_W1 = (const float*)d_in[14];
  const float* mlp_b1 = (const float*)d_in[15];
  const float* mlp_W2 = (const float*)d_in[16];
  const float* mlp_b2 = (const float*)d_in[17];
  const float* gru_w_ih = (const float*)d_in[18];
  const float* gru_w_hh = (const float*)d_in[19];
  const float* gru_b_ih = (const float*)d_in[20];
  const float* gru_b_hh = (const float*)d_in[21];

  char* ws = (char*)d_ws;
  size_t off = 0;
  auto alloc = [&](size_t bytes) { size_t o = off; off += (bytes + 255) & ~(size_t)255; return o; };
  bf16* W1blk = (bf16*)(ws + alloc((size_t)2 * 11 * 256 * 32 * 2));
  bf16* W2blk = (bf16*)(ws + alloc((size_t)2 * 2 * 8 * 128 * 32 * 2));
  bf16* wihblk = (bf16*)(ws + alloc((size_t)2 * 4 * 384 * 32 * 2));
  bf16* whhblk = (bf16*)(ws + alloc((size_t)2 * 4 * 384 * 32 * 2));
  float* w320 = (float*)(ws + alloc(512 * 4));
  float* time_emb = (float*)(ws + alloc((size_t)NB_EV * 32 * 4));
  float* edge_enc = (float*)(ws + alloc((size_t)NB_EV * 64 * 4));
  float* embA0 = (float*)(ws + alloc((size_t)NB_EV * ND * 4));
  float* embB0 = (float*)(ws + alloc((size_t)NB_EV * ND * 4));
  float* embA1 = (float*)(ws + alloc((size_t)NB_EV * ND * 4));
  float* embB1 = (float*)(ws + alloc((size_t)NB_EV * ND * 4));
  float* nb_out = (float*)(ws + alloc((size_t)4 * NB_EV * ND * 4));

  k_prep_weights<<<512, 256, 0, stream>>>(mlp_W1, mlp_W2, gru_w_ih, gru_w_hh,
                                          W1blk, W2blk, wihblk, whhblk, w320);
  k_prep_misc<<<2048, 256, 0, stream>>>(timestamps, t2v_w0, t2v_b0, t2v_w, t2v_b,
                                        srcn, dstn, memory, time_emb, embA0, embB0, nb_out);
  k_edge<<<NB_EV, 64, 0, stream>>>(edge_attrs, enc_W, enc_b, edge_enc);

  k_nbr<<<1024, 512, 0, stream>>>(
      srcn, dstn, memory, neighbor_ids, neighbor_times, neighbor_edge_attrs,
      t2v_w0, t2v_b0, t2v_w, t2v_b, W1blk, W2blk, w320, mlp_b1, mlp_b2, nb_out);

  k_event<<<2 * NB_EV / 64, 256, 0, stream>>>(
      0, embA0, embB0, embA1, ND, embB1, ND, time_emb, edge_enc,
      W1blk, W2blk, w320, mlp_b1, mlp_b2, nb_out,
      wihblk, whhblk, gru_b_ih, gru_b_hh);

  float* outf = (float*)d_out;
  k_event<<<2 * NB_EV / 64, 256, 0, stream>>>(
      1, embA1, embB1, outf, 2 * ND, outf + ND, 2 * ND, time_emb, edge_enc,
      W1blk, W2blk, w320, mlp_b1, mlp_b2, nb_out,
      wihblk, whhblk, gru_b_ih, gru_b_hh);
}

// Round 8
// 732.422 us; speedup vs baseline: 1.4664x; 1.4664x over previous
//
#include <hip/hip_runtime.h>
#include <math.h>

// TemporalGraphTower on MI355X (gfx950) — round 8.
// k_nbr: LDS cut to ~41KB (no xs tile — T-mode B-frags are gathered per-lane
// straight from global into registers; only t2v table + h hi/lo half-planes
// in LDS) -> 3 blocks/CU, 12 waves/CU: TLP hides weight/x load latency.
// Numerics = proven: bf16 M1 + fp32 rank-1 time fix, bf16 hi/lo 3-product M2,
// bf16 hi/lo 3-product GRU. k_event/prep = round 7 (passing).

typedef __bf16 bf16;
typedef __bf16 bf16x8 __attribute__((ext_vector_type(8)));
typedef float f32x4 __attribute__((ext_vector_type(4)));

#define MFMA16(a, b, c) __builtin_amdgcn_mfma_f32_16x16x32_bf16((a), (b), (c), 0, 0, 0)

__device__ __forceinline__ void split2(float v, bf16& hi, bf16& lo) {
  hi = (bf16)v;
  lo = (bf16)(v - (float)hi);
}

__device__ __forceinline__ bf16x8 cvt8(const float* __restrict__ p) {
  float4 a = *(const float4*)p;
  float4 b = *(const float4*)(p + 4);
  bf16x8 r;
  r[0] = (bf16)a.x; r[1] = (bf16)a.y; r[2] = (bf16)a.z; r[3] = (bf16)a.w;
  r[4] = (bf16)b.x; r[5] = (bf16)b.y; r[6] = (bf16)b.z; r[7] = (bf16)b.w;
  return r;
}

#define NB_EV 8192
#define ROWS_NB (NB_EV * 20)   // 163840
#define IN_DIM 352
#define HID 256
#define ND 128

// ---------------- prep: blocked weight layouts (round 7, proven) ----------
__global__ void k_prep_weights(const float* __restrict__ W1, const float* __restrict__ W2,
                               const float* __restrict__ wih, const float* __restrict__ whh,
                               bf16* __restrict__ W1blk, bf16* __restrict__ W2blk,
                               bf16* __restrict__ wihblk, bf16* __restrict__ whhblk,
                               float* __restrict__ w320) {
  const int NW1 = 2 * 11 * 256 * 32;   // 180224
  const int NW2 = 2 * 2 * 8 * 128 * 32; // 131072
  const int NG = 2 * 4 * 384 * 32;     // 98304
  int total = NW1 + NW2 + NG + NG + 512;
  for (int i = blockIdx.x * blockDim.x + threadIdx.x; i < total; i += gridDim.x * blockDim.x) {
    int j = i;
    if (j < NW1) {
      int l = j / 90112, r = j - l * 90112;
      int k0 = r / 8192, r2 = r & 8191;
      int n = r2 >> 5, ko = r2 & 31, k = k0 * 32 + ko;
      W1blk[j] = (bf16)W1[(l * 352 + k) * 256 + n];
    } else if ((j -= NW1) < NW2) {
      int l = j >> 16, r = j & 65535;
      int plane = r >> 15, r2 = r & 32767;
      int kg = r2 >> 12, r3 = r2 & 4095;
      int n = r3 >> 5, ko = r3 & 31, k = kg * 32 + ko;
      bf16 hi, lo; split2(W2[(l * 256 + k) * 128 + n], hi, lo);
      W2blk[j] = plane ? lo : hi;
    } else if ((j -= NW2) < NG) {
      int plane = j / 49152, r = j - plane * 49152;
      int kg = r / 12288, r2 = r - kg * 12288;
      int n = r2 >> 5, ko = r2 & 31, k = kg * 32 + ko;
      bf16 hi, lo; split2(wih[n * 128 + k], hi, lo);
      wihblk[j] = plane ? lo : hi;
    } else if ((j -= NG) < NG) {
      int plane = j / 49152, r = j - plane * 49152;
      int kg = r / 12288, r2 = r - kg * 12288;
      int n = r2 >> 5, ko = r2 & 31, k = kg * 32 + ko;
      bf16 hi, lo; split2(whh[n * 128 + k], hi, lo);
      whhblk[j] = plane ? lo : hi;
    } else {
      j -= NG;
      int l = j >> 8, n = j & 255;
      w320[j] = W1[(l * 352 + 320) * 256 + n];
    }
  }
}

__global__ void k_prep_misc(const float* __restrict__ ts, const float* __restrict__ w0,
                            const float* __restrict__ b0, const float* __restrict__ w,
                            const float* __restrict__ bb,
                            const int* __restrict__ srcn, const int* __restrict__ dstn,
                            const float* __restrict__ memory,
                            float* __restrict__ time_emb, float* __restrict__ embA0,
                            float* __restrict__ embB0, float* __restrict__ nb_out) {
  const int N1 = NB_EV * 32, N2 = NB_EV * ND, N3 = 4 * NB_EV * ND;
  int total = N1 + N2 + N3;
  float w0v = w0[0], b0v = b0[0];
  for (int i = blockIdx.x * blockDim.x + threadIdx.x; i < total; i += gridDim.x * blockDim.x) {
    int j = i;
    if (j < N1) {
      int b = j >> 5, c = j & 31;
      float t = ts[b];
      time_emb[j] = (c == 0) ? (w0v * t + b0v) : sinf(w[c - 1] * t + bb[c - 1]);
    } else if ((j -= N1) < N2) {
      int b = j >> 7, c = j & 127;
      embA0[j] = memory[(long)srcn[b] * ND + c];
      embB0[j] = memory[(long)dstn[b] * ND + c];
    } else {
      nb_out[j - N2] = 0.f;
    }
  }
}

__global__ void k_edge(const float* __restrict__ ea, const float* __restrict__ encW,
                       const float* __restrict__ encb, float* __restrict__ out) {
  __shared__ float row[64];
  int b = blockIdx.x, j = threadIdx.x;
  row[j] = ea[b * 64 + j];
  __syncthreads();
  float s = encb[j];
#pragma unroll
  for (int k = 0; k < 64; ++k) s += row[k] * encW[k * 64 + j];
  out[b * 64 + j] = s;
}

// ---------------- register-gather neighbor kernel ----------------
// grid (2560, 2): x = 64-row tile, y = side. 256 threads = 4 waves.
// T-mode MFMA: A = weight frag (global, L2-hot), B = x frag gathered per-lane
// from memory/nbe (L3-hot) straight into registers. LDS: t2v table + h hi/lo
// half-planes only (~41KB) -> 3 blocks/CU.
#define T2S 40         // t2v LDS stride (elems, 80B rows, 16B-aligned)
#define HSS2 136       // h half-plane stride (elems)
#define G_T2 0         // t2s  [64][40] bf16 = 5120
#define G_HHI 5120     // hhi  [64][136] bf16 = 17408
#define G_HLO 22528    // hlo  = 17408
#define G_CL 39936     // cl   f32[64]
#define G_TL 40192     // t_l  f32[64]
#define G_NB 40448     // nbid_l int[64]
#define G_NN 40704     // n_l   int[64]
#define G_FL 40960     // flat_l int[64]
#define G_TOT 41216
__global__ __launch_bounds__(256, 3) void k_nbr(
    const int* __restrict__ srcn, const int* __restrict__ dstn,
    const float* __restrict__ memory, const int* __restrict__ nbids,
    const float* __restrict__ nbt, const float* __restrict__ nbe,
    const float* __restrict__ w0p, const float* __restrict__ b0p,
    const float* __restrict__ wp, const float* __restrict__ bp,
    const bf16* __restrict__ W1blk, const bf16* __restrict__ W2blk,
    const float* __restrict__ w320, const float* __restrict__ b1,
    const float* __restrict__ b2, float* __restrict__ nb_out) {
  __shared__ __align__(16) char smem[G_TOT];
  bf16* t2s = (bf16*)(smem + G_T2);
  bf16* hhi = (bf16*)(smem + G_HHI);
  bf16* hlo = (bf16*)(smem + G_HLO);
  float* cl = (float*)(smem + G_CL);
  float* t_l = (float*)(smem + G_TL);
  int* nbid_l = (int*)(smem + G_NB);
  int* n_l = (int*)(smem + G_NN);
  int* flat_l = (int*)(smem + G_FL);

  const int tid = threadIdx.x;
  const int wid = tid >> 6, lane = tid & 63;
  const int colq = lane & 15, cq = lane >> 4;
  const int cq8 = cq * 8;
  const int side = blockIdx.y;
  const int r0 = blockIdx.x * 64;
  const int* nodes = side ? dstn : srcn;

  // phase A: per-row ids + linear time term
  if (tid < 64) {
    int rg = r0 + tid;
    int b = rg / 20, k = rg - b * 20;
    int n = nodes[b];
    int flat = n * 20 + k;
    nbid_l[tid] = nbids[flat];
    n_l[tid] = n;
    flat_l[tid] = flat;
    float t = nbt[flat];
    t_l[tid] = t;
    cl[tid] = w0p[0] * t + b0p[0];
  }
  __syncthreads();  // bar1

  // phase B: t2v table (col 0 zeroed) + per-lane row-id registers
  {
    int r = tid >> 2, c0 = (tid & 3) * 8;
    float t = t_l[r];
    union { bf16 h[8]; uint2 u[2]; } pk;
#pragma unroll
    for (int q = 0; q < 8; ++q) {
      int c = c0 + q;
      pk.h[q] = (c == 0) ? (bf16)0.f : (bf16)__sinf(wp[c - 1] * t + bp[c - 1]);
    }
    *(uint2*)&t2s[r * T2S + c0] = pk.u[0];
    *(uint2*)&t2s[r * T2S + c0 + 4] = pk.u[1];
  }
  long nbid_r[4], n_r[4], flat_r[4];
  float clr[4];
#pragma unroll
  for (int nr = 0; nr < 4; ++nr) {
    int row = nr * 16 + colq;
    nbid_r[nr] = nbid_l[row];
    n_r[nr] = n_l[row];
    flat_r[nr] = flat_l[row];
    clr[nr] = cl[row];
  }
  __syncthreads();  // bar2

#pragma unroll
  for (int layer = 0; layer < 2; ++layer) {
    // ---- M1-T: acc[mc][nr], wave owns cols {mc*64 + wid*16 + 0..15}
    const bf16* W1l = W1blk + layer * 90112 + (wid * 16 + colq) * 32 + cq8;
    f32x4 acc[4][4];
#pragma unroll
    for (int mc = 0; mc < 4; ++mc)
#pragma unroll
      for (int nr = 0; nr < 4; ++nr) acc[mc][nr] = (f32x4){0.f, 0.f, 0.f, 0.f};

#pragma unroll
    for (int k0 = 0; k0 < 11; ++k0) {
      bf16x8 xb[4];
#pragma unroll
      for (int nr = 0; nr < 4; ++nr) {
        if (k0 < 4)
          xb[nr] = cvt8(memory + nbid_r[nr] * ND + k0 * 32 + cq8);
        else if (k0 < 8)
          xb[nr] = cvt8(memory + n_r[nr] * ND + (k0 - 4) * 32 + cq8);
        else if (k0 < 10)
          xb[nr] = cvt8(nbe + flat_r[nr] * 64 + (k0 - 8) * 32 + cq8);
        else
          xb[nr] = *(const bf16x8*)(t2s + (nr * 16 + colq) * T2S + cq8);
      }
      bf16x8 wf[4];
#pragma unroll
      for (int mc = 0; mc < 4; ++mc)
        wf[mc] = *(const bf16x8*)(W1l + k0 * 8192 + mc * 64 * 32);
#pragma unroll
      for (int mc = 0; mc < 4; ++mc)
#pragma unroll
        for (int nr = 0; nr < 4; ++nr)
          acc[mc][nr] = MFMA16(wf[mc], xb[nr], acc[mc][nr]);
    }

    // rank-1 time fix + bias + relu (lane: row = nr*16+colq, 4 consecutive c)
    const float* w320l = w320 + layer * 256;
    const float* b1l = b1 + layer * 256;
#pragma unroll
    for (int mc = 0; mc < 4; ++mc) {
      int c0 = mc * 64 + wid * 16 + cq * 4;
      float4 wv = *(const float4*)&w320l[c0];
      float4 bv = *(const float4*)&b1l[c0];
#pragma unroll
      for (int nr = 0; nr < 4; ++nr) {
        float c = clr[nr];
        acc[mc][nr][0] = fmaxf(acc[mc][nr][0] + c * wv.x + bv.x, 0.f);
        acc[mc][nr][1] = fmaxf(acc[mc][nr][1] + c * wv.y + bv.y, 0.f);
        acc[mc][nr][2] = fmaxf(acc[mc][nr][2] + c * wv.z + bv.z, 0.f);
        acc[mc][nr][3] = fmaxf(acc[mc][nr][3] + c * wv.w + bv.w, 0.f);
      }
    }

    if (layer == 1) __syncthreads();  // bar6: layer-0 M2 reads done

    // M2 accumulators + pointers
    const bf16* W2h = W2blk + layer * 65536 + (wid * 32 + colq) * 32 + cq8;
    const bf16* W2l = W2h + 32768;
    f32x4 acc2[2][4];
#pragma unroll
    for (int mc2 = 0; mc2 < 2; ++mc2)
#pragma unroll
      for (int nr = 0; nr < 4; ++nr) acc2[mc2][nr] = (f32x4){0.f, 0.f, 0.f, 0.f};

    // two halves: dump h cols [h*128, h*128+128) then M2 over kg = h*4..h*4+3
#pragma unroll
    for (int hh = 0; hh < 2; ++hh) {
      // dump: mc = 2*hh, 2*hh+1 -> local cols (mc&1)*64 + wid*16 + cq*4
#pragma unroll
      for (int mq = 0; mq < 2; ++mq) {
        int mc = hh * 2 + mq;
        int cl0 = mq * 64 + wid * 16 + cq * 4;
#pragma unroll
        for (int nr = 0; nr < 4; ++nr) {
          int r = nr * 16 + colq;
          union { bf16 h[4]; uint2 u; } ph, pl;
#pragma unroll
          for (int i = 0; i < 4; ++i) split2(acc[mc][nr][i], ph.h[i], pl.h[i]);
          *(uint2*)&hhi[r * HSS2 + cl0] = ph.u;
          *(uint2*)&hlo[r * HSS2 + cl0] = pl.u;
        }
      }
      __syncthreads();  // dump visible

#pragma unroll
      for (int kq = 0; kq < 4; ++kq) {
        int kg = hh * 4 + kq;
        bf16x8 bh[4], bl[4];
#pragma unroll
        for (int nr = 0; nr < 4; ++nr) {
          int r = nr * 16 + colq;
          bh[nr] = *(const bf16x8*)(hhi + r * HSS2 + kq * 32 + cq8);
          bl[nr] = *(const bf16x8*)(hlo + r * HSS2 + kq * 32 + cq8);
        }
        bf16x8 wh[2], wl[2];
#pragma unroll
        for (int mc2 = 0; mc2 < 2; ++mc2) {
          wh[mc2] = *(const bf16x8*)(W2h + kg * 4096 + mc2 * 512);
          wl[mc2] = *(const bf16x8*)(W2l + kg * 4096 + mc2 * 512);
        }
#pragma unroll
        for (int mc2 = 0; mc2 < 2; ++mc2)
#pragma unroll
          for (int nr = 0; nr < 4; ++nr) {
            acc2[mc2][nr] = MFMA16(wh[mc2], bh[nr], acc2[mc2][nr]);
            acc2[mc2][nr] = MFMA16(wl[mc2], bh[nr], acc2[mc2][nr]);
            acc2[mc2][nr] = MFMA16(wh[mc2], bl[nr], acc2[mc2][nr]);
          }
      }
      if (hh == 0) __syncthreads();  // half-0 reads done before half-1 dump
    }

    // ---- segmented mean over k (4 events per tile), registers + shfl
    {
      const float* b2l = b2 + layer * 128;
      long zbase = (long)(layer * 2 + side) * NB_EV * ND;
      int b0 = r0 / 20;
#pragma unroll
      for (int e = 0; e < 4; ++e) {
        int b = b0 + e;
        int lo = b * 20 - r0, hi = lo + 20;
        int cnt = min(hi, 64) - max(lo, 0);
        if (cnt <= 0) continue;
        f32x4 v[2];
#pragma unroll
        for (int mc2 = 0; mc2 < 2; ++mc2) {
          v[mc2] = (f32x4){0.f, 0.f, 0.f, 0.f};
#pragma unroll
          for (int nr = 0; nr < 4; ++nr) {
            int rl = nr * 16 + colq;
            if (rl >= lo && rl < hi) v[mc2] += acc2[mc2][nr];
          }
        }
#pragma unroll
        for (int s = 1; s < 16; s <<= 1) {
#pragma unroll
          for (int mc2 = 0; mc2 < 2; ++mc2) {
            v[mc2][0] += __shfl_xor(v[mc2][0], s);
            v[mc2][1] += __shfl_xor(v[mc2][1], s);
            v[mc2][2] += __shfl_xor(v[mc2][2], s);
            v[mc2][3] += __shfl_xor(v[mc2][3], s);
          }
        }
        if (colq == e) {
          float fc = (float)cnt;
#pragma unroll
          for (int mc2 = 0; mc2 < 2; ++mc2) {
            int c = wid * 32 + mc2 * 16 + cq * 4;
            float4 bv = *(const float4*)&b2l[c];
            atomicAdd(&nb_out[zbase + (long)b * ND + c + 0], (v[mc2][0] + fc * bv.x) * 0.05f);
            atomicAdd(&nb_out[zbase + (long)b * ND + c + 1], (v[mc2][1] + fc * bv.y) * 0.05f);
            atomicAdd(&nb_out[zbase + (long)b * ND + c + 2], (v[mc2][2] + fc * bv.z) * 0.05f);
            atomicAdd(&nb_out[zbase + (long)b * ND + c + 3], (v[mc2][3] + fc * bv.w) * 0.05f);
          }
        }
      }
    }
  }
}

// ---------------- event chain: MLP + GRU (round 7, passing) ----------------
#define XSS 360
#define HSS 136
#define E_G 46080
#define E_CL 80896
#define E_TOT 81152
__global__ __launch_bounds__(256, 1) void k_event(
    int layer, const float* __restrict__ embA_in, const float* __restrict__ embB_in,
    float* __restrict__ outA, int ostrideA, float* __restrict__ outB, int ostrideB,
    const float* __restrict__ time_emb, const float* __restrict__ edge_enc,
    const bf16* __restrict__ W1blk, const bf16* __restrict__ W2blk,
    const float* __restrict__ w320, const float* __restrict__ b1,
    const float* __restrict__ b2, const float* __restrict__ nb_out,
    const bf16* __restrict__ wihblk, const bf16* __restrict__ whhblk,
    const float* __restrict__ bih, const float* __restrict__ bhh) {
  __shared__ __align__(16) char smem[E_TOT];
  bf16* xs = (bf16*)(smem);
  bf16* hhi = (bf16*)(smem);
  bf16* hlo = (bf16*)(smem + 17408);
  bf16* mhi = (bf16*)(smem);
  bf16* mlo = (bf16*)(smem + 17408);
  bf16* ghi = (bf16*)(smem + E_G);
  bf16* glo = (bf16*)(smem + E_G + 17408);
  float* cl = (float*)(smem + E_CL);

  const int tid = threadIdx.x;
  const int r0 = blockIdx.x * 64;
  const int side = r0 >> 13;
  const int b0r = r0 & (NB_EV - 1);
  const float* ea = side ? embB_in : embA_in;
  const float* eb = side ? embA_in : embB_in;

  if (tid < 64) cl[tid] = time_emb[(b0r + tid) * 32];

  for (int task = tid; task < 64 * 88; task += 256) {
    int r = task / 88; int c = (task - r * 88) * 4;
    int b = b0r + r;
    float4 v;
    if (c < 128) {
      v = *(const float4*)&ea[(long)b * ND + c];
      bf16 h0, l0, h1, l1, h2, l2, h3, l3;
      split2(v.x, h0, l0); split2(v.y, h1, l1); split2(v.z, h2, l2); split2(v.w, h3, l3);
      ghi[r * HSS + c + 0] = h0; glo[r * HSS + c + 0] = l0;
      ghi[r * HSS + c + 1] = h1; glo[r * HSS + c + 1] = l1;
      ghi[r * HSS + c + 2] = h2; glo[r * HSS + c + 2] = l2;
      ghi[r * HSS + c + 3] = h3; glo[r * HSS + c + 3] = l3;
    } else if (c < 256) {
      v = *(const float4*)&eb[(long)b * ND + (c - 128)];
    } else if (c < 320) {
      v = *(const float4*)&edge_enc[(long)b * 64 + (c - 256)];
    } else {
      float vv[4];
#pragma unroll
      for (int q = 0; q < 4; ++q) {
        int cc = c + q - 320;
        vv[q] = (cc == 0) ? 0.f : time_emb[b * 32 + cc];
      }
      v = make_float4(vv[0], vv[1], vv[2], vv[3]);
    }
    union { bf16 h[4]; uint2 u; } pk;
    pk.h[0] = (bf16)v.x; pk.h[1] = (bf16)v.y; pk.h[2] = (bf16)v.z; pk.h[3] = (bf16)v.w;
    *(uint2*)&xs[r * XSS + c] = pk.u;
  }
  __syncthreads();

  const int wid = tid >> 6, lane = tid & 63;
  const int colq = lane & 15, cq = lane >> 4;
  const int rsub = cq * 4;

  const bf16* W1l = W1blk + layer * 90112 + (wid * 64 + colq) * 32 + cq * 8;
  const bf16* xsl = xs + colq * XSS + cq * 8;
  f32x4 acc[4][4];
#pragma unroll
  for (int m = 0; m < 4; ++m)
#pragma unroll
    for (int n = 0; n < 4; ++n) acc[m][n] = (f32x4){0.f, 0.f, 0.f, 0.f};
#pragma unroll
  for (int k0 = 0; k0 < 11; ++k0) {
    bf16x8 a[4], b[4];
#pragma unroll
    for (int m = 0; m < 4; ++m) a[m] = *(const bf16x8*)(xsl + m * 16 * XSS + k0 * 32);
#pragma unroll
    for (int n = 0; n < 4; ++n) b[n] = *(const bf16x8*)(W1l + k0 * 8192 + n * 512);
#pragma unroll
    for (int m = 0; m < 4; ++m)
#pragma unroll
      for (int n = 0; n < 4; ++n) acc[m][n] = MFMA16(a[m], b[n], acc[m][n]);
  }
  __syncthreads();

  const float* w320l = w320 + layer * 256;
  const float* b1l = b1 + layer * 256;
#pragma unroll
  for (int n = 0; n < 4; ++n) {
    int cg = wid * 64 + n * 16 + colq;
    float wv = w320l[cg], bv = b1l[cg];
#pragma unroll
    for (int m = 0; m < 4; ++m)
#pragma unroll
      for (int i = 0; i < 4; ++i) {
        int r = m * 16 + rsub + i;
        acc[m][n][i] = fmaxf(acc[m][n][i] + cl[r] * wv + bv, 0.f);
      }
  }
  if (wid < 2) {
#pragma unroll
    for (int m = 0; m < 4; ++m)
#pragma unroll
      for (int n = 0; n < 4; ++n)
#pragma unroll
        for (int i = 0; i < 4; ++i) {
          int r = m * 16 + rsub + i;
          int cc = wid * 64 + n * 16 + colq;
          bf16 hi, lo; split2(acc[m][n][i], hi, lo);
          hhi[r * HSS + cc] = hi;
          hlo[r * HSS + cc] = lo;
        }
  }
  __syncthreads();

  const bf16* W2h = W2blk + layer * 65536 + (wid * 32 + colq) * 32 + cq * 8;
  const bf16* W2l = W2h + 32768;
  const bf16* hhil = hhi + colq * HSS + cq * 8;
  const bf16* hlol = hlo + colq * HSS + cq * 8;
  f32x4 acc2[4][2];
#pragma unroll
  for (int m = 0; m < 4; ++m)
#pragma unroll
    for (int n = 0; n < 2; ++n) acc2[m][n] = (f32x4){0.f, 0.f, 0.f, 0.f};
#pragma unroll
  for (int kg = 0; kg < 8; ++kg) {
    if (kg == 4) {
      __syncthreads();
      if (wid >= 2) {
#pragma unroll
        for (int m = 0; m < 4; ++m)
#pragma unroll
          for (int n = 0; n < 4; ++n)
#pragma unroll
            for (int i = 0; i < 4; ++i) {
              int r = m * 16 + rsub + i;
              int cc = (wid & 1) * 64 + n * 16 + colq;
              bf16 hi, lo; split2(acc[m][n][i], hi, lo);
              hhi[r * HSS + cc] = hi;
              hlo[r * HSS + cc] = lo;
            }
      }
      __syncthreads();
    }
    int lk = (kg & 3) * 32;
    bf16x8 ahi[4], alo[4], bhi[2], blo[2];
#pragma unroll
    for (int m = 0; m < 4; ++m) {
      ahi[m] = *(const bf16x8*)(hhil + m * 16 * HSS + lk);
      alo[m] = *(const bf16x8*)(hlol + m * 16 * HSS + lk);
    }
#pragma unroll
    for (int n = 0; n < 2; ++n) {
      bhi[n] = *(const bf16x8*)(W2h + kg * 4096 + n * 512);
      blo[n] = *(const bf16x8*)(W2l + kg * 4096 + n * 512);
    }
#pragma unroll
    for (int m = 0; m < 4; ++m)
#pragma unroll
      for (int n = 0; n < 2; ++n) {
        acc2[m][n] = MFMA16(ahi[m], bhi[n], acc2[m][n]);
        acc2[m][n] = MFMA16(ahi[m], blo[n], acc2[m][n]);
        acc2[m][n] = MFMA16(alo[m], bhi[n], acc2[m][n]);
      }
  }
  __syncthreads();

  const float* b2l = b2 + layer * 128;
  const float* nbl = nb_out + ((long)(layer * 2 + side)) * NB_EV * ND;
#pragma unroll
  for (int n = 0; n < 2; ++n) {
    int cg = wid * 32 + n * 16 + colq;
    float bv = b2l[cg];
#pragma unroll
    for (int m = 0; m < 4; ++m)
#pragma unroll
      for (int i = 0; i < 4; ++i) {
        int r = m * 16 + rsub + i;
        float mval = acc2[m][n][i] + bv + nbl[(long)(b0r + r) * ND + cg];
        bf16 hi, lo; split2(mval, hi, lo);
        mhi[r * HSS + cg] = hi;
        mlo[r * HSS + cg] = lo;
      }
  }
  __syncthreads();

  float* outP = side ? outB : outA;
  const int ostride = side ? ostrideB : ostrideA;
  const int rowA = wid * 16 + colq;
  const int rbase = wid * 16 + rsub;
  const bf16* mhil = mhi + rowA * HSS + cq * 8;
  const bf16* mlol = mlo + rowA * HSS + cq * 8;
  const bf16* ghil = ghi + rowA * HSS + cq * 8;
  const bf16* glol = glo + rowA * HSS + cq * 8;
  const bf16* wihl = wihblk + colq * 32 + cq * 8;
  const bf16* whhl = whhblk + colq * 32 + cq * 8;

  for (int jt = 0; jt < 8; ++jt) {
    f32x4 gx[3], gh[3];
#pragma unroll
    for (int g = 0; g < 3; ++g) {
      gx[g] = (f32x4){0.f, 0.f, 0.f, 0.f};
      gh[g] = (f32x4){0.f, 0.f, 0.f, 0.f};
    }
#pragma unroll
    for (int kc = 0; kc < 4; ++kc) {
      bf16x8 amh = *(const bf16x8*)(mhil + kc * 32);
      bf16x8 aml = *(const bf16x8*)(mlol + kc * 32);
      bf16x8 ahh = *(const bf16x8*)(ghil + kc * 32);
      bf16x8 ahl = *(const bf16x8*)(glol + kc * 32);
#pragma unroll
      for (int g = 0; g < 3; ++g) {
        int nb = (g * 128 + jt * 16) * 32;
        bf16x8 bh = *(const bf16x8*)(wihl + kc * 12288 + nb);
        bf16x8 bl = *(const bf16x8*)(wihl + 49152 + kc * 12288 + nb);
        gx[g] = MFMA16(amh, bh, gx[g]);
        gx[g] = MFMA16(aml, bh, gx[g]);
        gx[g] = MFMA16(amh, bl, gx[g]);
        bf16x8 ch = *(const bf16x8*)(whhl + kc * 12288 + nb);
        bf16x8 cl2 = *(const bf16x8*)(whhl + 49152 + kc * 12288 + nb);
        gh[g] = MFMA16(ahh, ch, gh[g]);
        gh[g] = MFMA16(ahl, ch, gh[g]);
        gh[g] = MFMA16(ahh, cl2, gh[g]);
      }
    }
    int j = jt * 16 + colq;
    float bihr = bih[j], bihz = bih[128 + j], bihn = bih[256 + j];
    float bhhr = bhh[j], bhhz = bhh[128 + j], bhhn = bhh[256 + j];
#pragma unroll
    for (int i = 0; i < 4; ++i) {
      int rr = rbase + i;
      float rx = gx[0][i] + bihr, zx = gx[1][i] + bihz, nx = gx[2][i] + bihn;
      float rh = gh[0][i] + bhhr, zh = gh[1][i] + bhhz, nh = gh[2][i] + bhhn;
      float r = 1.f / (1.f + expf(-(rx + rh)));
      float zz = 1.f / (1.f + expf(-(zx + zh)));
      float n = tanhf(nx + r * nh);
      float hval = (float)ghi[rr * HSS + j] + (float)glo[rr * HSS + j];
      outP[(long)(b0r + rr) * ostride + j] = (1.f - zz) * n + zz * hval;
    }
  }
}

// ---------------- launch ----------------
extern "C" void kernel_launch(void* const* d_in, const int* in_sizes, int n_in,
                              void* d_out, int out_size, void* d_ws, size_t ws_size,
                              hipStream_t stream) {
  const int* srcn = (const int*)d_in[0];
  const int* dstn = (const int*)d_in[1];
  const float* edge_attrs = (const float*)d_in[2];
  const float* timestamps = (const float*)d_in[3];
  const float* memory = (const float*)d_in[4];
  const int* neighbor_ids = (const int*)d_in[5];
  const float* neighbor_times = (const float*)d_in[6];
  const float* neighbor_edge_attrs = (const float*)d_in[7];
  const float* t2v_w0 = (const float*)d_in[8];
  const float* t2v_b0 = (const float*)d_in[9];
  const float* t2v_w = (const float*)d_in[10];
  const float* t2v_b = (const float*)d_in[11];
  const float* enc_W = (const float*)d_in[12];
  const float* enc_b = (const float*)d_in[13];
  const float* mlp_W1 = (const float*)d_in[14];
  const float* mlp_b1 = (const float*)d_in[15];
  const float* mlp_W2 = (const float*)d_in[16];
  const float* mlp_b2 = (const float*)d_in[17];
  const float* gru_w_ih = (const float*)d_in[18];
  const float* gru_w_hh = (const float*)d_in[19];
  const float* gru_b_ih = (const float*)d_in[20];
  const float* gru_b_hh = (const float*)d_in[21];

  char* ws = (char*)d_ws;
  size_t off = 0;
  auto alloc = [&](size_t bytes) { size_t o = off; off += (bytes + 255) & ~(size_t)255; return o; };
  bf16* W1blk = (bf16*)(ws + alloc((size_t)2 * 11 * 256 * 32 * 2));
  bf16* W2blk = (bf16*)(ws + alloc((size_t)2 * 2 * 8 * 128 * 32 * 2));
  bf16* wihblk = (bf16*)(ws + alloc((size_t)2 * 4 * 384 * 32 * 2));
  bf16* whhblk = (bf16*)(ws + alloc((size_t)2 * 4 * 384 * 32 * 2));
  float* w320 = (float*)(ws + alloc(512 * 4));
  float* time_emb = (float*)(ws + alloc((size_t)NB_EV * 32 * 4));
  float* edge_enc = (float*)(ws + alloc((size_t)NB_EV * 64 * 4));
  float* embA0 = (float*)(ws + alloc((size_t)NB_EV * ND * 4));
  float* embB0 = (float*)(ws + alloc((size_t)NB_EV * ND * 4));
  float* embA1 = (float*)(ws + alloc((size_t)NB_EV * ND * 4));
  float* embB1 = (float*)(ws + alloc((size_t)NB_EV * ND * 4));
  float* nb_out = (float*)(ws + alloc((size_t)4 * NB_EV * ND * 4));

  k_prep_weights<<<512, 256, 0, stream>>>(mlp_W1, mlp_W2, gru_w_ih, gru_w_hh,
                                          W1blk, W2blk, wihblk, whhblk, w320);
  k_prep_misc<<<2048, 256, 0, stream>>>(timestamps, t2v_w0, t2v_b0, t2v_w, t2v_b,
                                        srcn, dstn, memory, time_emb, embA0, embB0, nb_out);
  k_edge<<<NB_EV, 64, 0, stream>>>(edge_attrs, enc_W, enc_b, edge_enc);

  k_nbr<<<dim3(ROWS_NB / 64, 2, 1), 256, 0, stream>>>(
      srcn, dstn, memory, neighbor_ids, neighbor_times, neighbor_edge_attrs,
      t2v_w0, t2v_b0, t2v_w, t2v_b, W1blk, W2blk, w320, mlp_b1, mlp_b2, nb_out);

  k_event<<<2 * NB_EV / 64, 256, 0, stream>>>(
      0, embA0, embB0, embA1, ND, embB1, ND, time_emb, edge_enc,
      W1blk, W2blk, w320, mlp_b1, mlp_b2, nb_out,
      wihblk, whhblk, gru_b_ih, gru_b_hh);

  float* outf = (float*)d_out;
  k_event<<<2 * NB_EV / 64, 256, 0, stream>>>(
      1, embA1, embB1, outf, 2 * ND, outf + ND, 2 * ND, time_emb, edge_enc,
      W1blk, W2blk, w320, mlp_b1, mlp_b2, nb_out,
      wihblk, whhblk, gru_b_ih, gru_b_hh);
}